// Round 8
// baseline (248.731 us; speedup 1.0000x reference)
//
#include <hip/hip_runtime.h>
#include <hip/hip_bf16.h>
#include <math.h>

// GQA attention forward, MI355X. Round 8: r7 barrier-free design with the
// causal-mask wave-offset bug fixed (16*w term restored).
// All MFMA fragments loaded directly global->register (L2-resident operands,
// 16B/lane contiguous); no cooperative LDS staging, zero __syncthreads in
// main loops. attn keeps only a wave-private LDS strip for the P round trip.
// ws (u16): Xq 2M | Xk 2M | Xv 2M | Wt 1.5M | wot 1M | Qr 2M | Kr 512K | Vrt 512K | AO 2M

#define SEQ 2048
#define DM 1024
#define HD 64

using u16 = unsigned short;
typedef __attribute__((ext_vector_type(8))) short bf16x8;
typedef __attribute__((ext_vector_type(4))) float f32x4;

// 1/sqrt(64) * log2(e): softmax in exp2 domain.
#define QSCALE 0.18033688011112042f

__device__ __forceinline__ u16 f2b(float f) {              // RNE
    union { float f; unsigned int i; } v; v.f = f;
    unsigned int u = v.i;
    return (u16)((u + 0x7fffu + ((u >> 16) & 1u)) >> 16);
}
__device__ __forceinline__ u16 f2b_fast(float f) {         // biased round
    union { float f; unsigned int i; } v; v.f = f;
    return (u16)((v.i + 0x8000u) >> 16);
}

// ---------------------------------------------------------------- prep
// [0,640): weight 64x64 transposes fp32->bf16 row-major [n][k]:
//   Wq->Wt[0..1023], Wk->Wt[+1024], Wv->Wt[+1280], Wo->wot.
// [640,1408): q/k/v fp32 -> bf16 row-major.
__global__ __launch_bounds__(256) void prep_kernel(
    const float* __restrict__ qin, const float* __restrict__ kin, const float* __restrict__ vin,
    const float* __restrict__ Wq, const float* __restrict__ Wk,
    const float* __restrict__ Wv, const float* __restrict__ Wo,
    u16* __restrict__ Xq, u16* __restrict__ Xk, u16* __restrict__ Xv,
    u16* __restrict__ Wt, u16* __restrict__ wot)
{
    const int b = blockIdx.x;
    const int t = threadIdx.x;

    if (b < 640) {
        __shared__ short T[64][72];
        const float* W; u16* dst; int N, t0, rowoff;
        if (b < 256)      { W = Wq; dst = Wt;  N = 1024; t0 = b;       rowoff = 0; }
        else if (b < 320) { W = Wk; dst = Wt;  N = 256;  t0 = b - 256; rowoff = 1024; }
        else if (b < 384) { W = Wv; dst = Wt;  N = 256;  t0 = b - 320; rowoff = 1280; }
        else              { W = Wo; dst = wot; N = 1024; t0 = b - 384; rowoff = 0; }
        const int ntn = N >> 6;
        const int k0 = (t0 / ntn) * 64, n0 = (t0 % ntn) * 64;
        const int r = t >> 4, c4 = (t & 15) * 4;
        #pragma unroll
        for (int rr = 0; rr < 4; ++rr) {
            const int k = r + rr * 16;
            float4 w4 = *reinterpret_cast<const float4*>(W + (size_t)(k0 + k) * N + n0 + c4);
            T[c4 + 0][k] = (short)f2b(w4.x);
            T[c4 + 1][k] = (short)f2b(w4.y);
            T[c4 + 2][k] = (short)f2b(w4.z);
            T[c4 + 3][k] = (short)f2b(w4.w);
        }
        __syncthreads();
        const int n = t >> 2, ck = (t & 3) * 16;
        u16* dp = dst + (size_t)(rowoff + n0 + n) * DM + k0 + ck;
        *reinterpret_cast<bf16x8*>(dp)     = *reinterpret_cast<const bf16x8*>(&T[n][ck]);
        *reinterpret_cast<bf16x8*>(dp + 8) = *reinterpret_cast<const bf16x8*>(&T[n][ck + 8]);
    } else {
        const int idx = b - 640;
        const int which = idx >> 8;                 // 256 blocks per tensor
        const int ib = idx & 255;
        const float* src = (which == 0) ? qin : (which == 1) ? kin : vin;
        u16* dst = (which == 0) ? Xq : (which == 1) ? Xk : Xv;
        const size_t base = (size_t)ib * 8192 + (size_t)t * 32;
        #pragma unroll
        for (int c = 0; c < 4; ++c) {
            float4 x0 = *reinterpret_cast<const float4*>(src + base + c * 8);
            float4 x1 = *reinterpret_cast<const float4*>(src + base + c * 8 + 4);
            bf16x8 o;
            o[0] = (short)f2b(x0.x); o[1] = (short)f2b(x0.y);
            o[2] = (short)f2b(x0.z); o[3] = (short)f2b(x0.w);
            o[4] = (short)f2b(x1.x); o[5] = (short)f2b(x1.y);
            o[6] = (short)f2b(x1.z); o[7] = (short)f2b(x1.w);
            *reinterpret_cast<bf16x8*>(dst + base + c * 8) = o;
        }
    }
}

// ---------------------------------------------------------------- projections
// Barrier-free: grid (24, 32), 4 waves/block in 2x2, each wave a 32x32 tile.
// Fragments loaded directly from global. Cols [0,1024)=Q, [1024,1280)=K,
// [1280,1536)=V.
__global__ __launch_bounds__(256) void proj_mfma(
    const u16* __restrict__ Xq, const u16* __restrict__ Xk, const u16* __restrict__ Xv,
    const u16* __restrict__ Wt,
    const float* __restrict__ bq, const float* __restrict__ bk, const float* __restrict__ bv,
    u16* __restrict__ Qr, u16* __restrict__ Kr, u16* __restrict__ Vrt)
{
    const int t = threadIdx.x;
    const int w = t >> 6, lane = t & 63, lm = lane & 15, quad = lane >> 4;
    const int n0 = blockIdx.x * 64 + (w & 1) * 32;
    const int m0 = blockIdx.y * 64 + (w >> 1) * 32;
    const int zone = (n0 < 1024) ? 0 : (n0 < 1280) ? 1 : 2;
    const u16* __restrict__ Az = (zone == 0) ? Xq : (zone == 1) ? Xk : Xv;

    const u16* arow[2] = { Az + (size_t)(m0 + lm) * DM + quad * 8,
                           Az + (size_t)(m0 + 16 + lm) * DM + quad * 8 };
    const u16* brow[2] = { Wt + (size_t)(n0 + lm) * DM + quad * 8,
                           Wt + (size_t)(n0 + 16 + lm) * DM + quad * 8 };

    f32x4 acc[2][2];
    #pragma unroll
    for (int i = 0; i < 2; ++i)
        #pragma unroll
        for (int j = 0; j < 2; ++j) acc[i][j] = (f32x4){0.f, 0.f, 0.f, 0.f};

    bf16x8 a0[2], b0[2], a1[2], b1[2];
    #pragma unroll
    for (int i = 0; i < 2; ++i) {
        a0[i] = *reinterpret_cast<const bf16x8*>(arow[i]);
        b0[i] = *reinterpret_cast<const bf16x8*>(brow[i]);
    }
    for (int k = 0; k < DM; k += 64) {
        #pragma unroll
        for (int i = 0; i < 2; ++i) {
            a1[i] = *reinterpret_cast<const bf16x8*>(arow[i] + k + 32);
            b1[i] = *reinterpret_cast<const bf16x8*>(brow[i] + k + 32);
        }
        #pragma unroll
        for (int mi = 0; mi < 2; ++mi)
            #pragma unroll
            for (int ni = 0; ni < 2; ++ni)
                acc[mi][ni] = __builtin_amdgcn_mfma_f32_16x16x32_bf16(a0[mi], b0[ni], acc[mi][ni], 0, 0, 0);
        if (k + 64 < DM) {
            #pragma unroll
            for (int i = 0; i < 2; ++i) {
                a0[i] = *reinterpret_cast<const bf16x8*>(arow[i] + k + 64);
                b0[i] = *reinterpret_cast<const bf16x8*>(brow[i] + k + 64);
            }
        }
        #pragma unroll
        for (int mi = 0; mi < 2; ++mi)
            #pragma unroll
            for (int ni = 0; ni < 2; ++ni)
                acc[mi][ni] = __builtin_amdgcn_mfma_f32_16x16x32_bf16(a1[mi], b1[ni], acc[mi][ni], 0, 0, 0);
    }

    const float* __restrict__ bias = (zone == 0) ? bq : (zone == 1) ? bk : bv;
    const int zoff = (zone == 0) ? 0 : (zone == 1) ? 1024 : 1280;
    #pragma unroll
    for (int mi = 0; mi < 2; ++mi)
        #pragma unroll
        for (int ni = 0; ni < 2; ++ni) {
            const int zc = (n0 - zoff) + ni * 16 + lm;   // col within zone
            const int head = zc >> 6, d = zc & 63;
            const float bvv = bias[zc];
            float vals[4];
            #pragma unroll
            for (int r = 0; r < 4; ++r) vals[r] = acc[mi][ni][r] + bvv;
            if (zone != 2) {
                const int pi = d >> 1;
                const float theta = exp2f(-0.8304820237f * (float)pi);  // 10000^(-pi/16)
                const bool odd = (lm & 1);
                const float sca = (zone == 0) ? QSCALE : 1.0f;
                u16* op = (zone == 0 ? Qr : Kr) + (size_t)head * SEQ * HD;
                #pragma unroll
                for (int r = 0; r < 4; ++r) {
                    const int m = m0 + mi * 16 + quad * 4 + r;
                    float sn, cs;
                    sincosf((float)m * theta, &sn, &cs);
                    float x  = vals[r];
                    float xp = __shfl_xor(x, 1);
                    float o  = (odd ? (xp * sn + x * cs) : (x * cs - xp * sn)) * sca;
                    op[(size_t)m * HD + d] = f2b(o);
                }
            } else {      // V transposed [kvh][d][s]
                u16 pk[4];
                #pragma unroll
                for (int r = 0; r < 4; ++r) pk[r] = f2b(vals[r]);
                const int m = m0 + mi * 16 + quad * 4;
                u16* vp = Vrt + ((size_t)head * HD + d) * SEQ + m;
                *reinterpret_cast<uint2*>(vp) = *reinterpret_cast<uint2*>(pk);
            }
        }
}

// ---------------------------------------------------------------- attention
// grid (16 heads, 32 qy), barrier-free. Wave w owns q-rows [16w,16w+16);
// K/V/Q frags direct from global (L2-hot); P via wave-private LDS strip;
// fixed-base exp2 softmax. FIX vs r7: causal mask includes the 16*w row offset.
__global__ __launch_bounds__(256) void attn_mfma(
    const u16* __restrict__ Qr, const u16* __restrict__ Kr, const u16* __restrict__ Vrt,
    u16* __restrict__ AO)
{
    const int h  = blockIdx.x;
    const int qy = blockIdx.y;
    const int qt = (qy < 16) ? (2 * qy) : (63 - 2 * qy);   // balanced pairing
    const int kvh = h & 3;

    __shared__ u16 Ps[4][16][76];

    const int t = threadIdx.x;
    const int w = t >> 6, lane = t & 63, lm = lane & 15, quad = lane >> 4;

    const u16* qp = Qr + ((size_t)h * SEQ + qt * 64 + 16 * w + lm) * HD + quad * 8;
    const bf16x8 aq0 = *reinterpret_cast<const bf16x8*>(qp);
    const bf16x8 aq1 = *reinterpret_cast<const bf16x8*>(qp + 32);

    const u16* krow = Kr  + ((size_t)kvh * SEQ + lm) * HD + quad * 8;   // + key*HD
    const u16* vrow = Vrt + ((size_t)kvh * HD + lm) * SEQ + quad * 8;   // + db*16*SEQ + key

    f32x4 O[4] = { {0,0,0,0}, {0,0,0,0}, {0,0,0,0}, {0,0,0,0} };   // C[q=quad*4+r][d=16db+lm]
    float lp[4] = { 0.f, 0.f, 0.f, 0.f };

    u16* ps = &Ps[w][0][0];

    for (int kt = 0; kt <= qt; ++kt) {
        const int kb = kt * 64;
        bf16x8 kb0[4], kb1[4], vb0[4], vb1[4];
        #pragma unroll
        for (int nb = 0; nb < 4; ++nb) {
            const u16* kp = krow + (size_t)(kb + 16 * nb) * HD;
            kb0[nb] = *reinterpret_cast<const bf16x8*>(kp);
            kb1[nb] = *reinterpret_cast<const bf16x8*>(kp + 32);
        }
        #pragma unroll
        for (int db = 0; db < 4; ++db) {
            const u16* vp = vrow + (size_t)(16 * db) * SEQ + kb;
            vb0[db] = *reinterpret_cast<const bf16x8*>(vp);
            vb1[db] = *reinterpret_cast<const bf16x8*>(vp + 32);
        }

        f32x4 s[4];
        #pragma unroll
        for (int nb = 0; nb < 4; ++nb) {
            f32x4 zz = { 0.f, 0.f, 0.f, 0.f };
            zz = __builtin_amdgcn_mfma_f32_16x16x32_bf16(aq0, kb0[nb], zz, 0, 0, 0);
            s[nb] = __builtin_amdgcn_mfma_f32_16x16x32_bf16(aq1, kb1[nb], zz, 0, 0, 0);
        }

        if (kt == qt) {   // causal mask on diagonal tile (global col > global row)
            #pragma unroll
            for (int nb = 0; nb < 4; ++nb)
                #pragma unroll
                for (int r = 0; r < 4; ++r)
                    if (16 * nb + lm > 16 * w + quad * 4 + r) s[nb][r] = -INFINITY;
        }

        #pragma unroll
        for (int nb = 0; nb < 4; ++nb)
            #pragma unroll
            for (int r = 0; r < 4; ++r) {
                float e = __builtin_amdgcn_exp2f(fminf(s[nb][r], 126.f));
                lp[r] += e;
                ps[(quad * 4 + r) * 76 + 16 * nb + lm] = f2b_fast(e);
            }

        const bf16x8 ap0 = *reinterpret_cast<const bf16x8*>(&ps[lm * 76 + quad * 8]);
        const bf16x8 ap1 = *reinterpret_cast<const bf16x8*>(&ps[lm * 76 + 32 + quad * 8]);
        #pragma unroll
        for (int db = 0; db < 4; ++db) {
            O[db] = __builtin_amdgcn_mfma_f32_16x16x32_bf16(ap0, vb0[db], O[db], 0, 0, 0);
            O[db] = __builtin_amdgcn_mfma_f32_16x16x32_bf16(ap1, vb1[db], O[db], 0, 0, 0);
        }
    }

    #pragma unroll
    for (int r = 0; r < 4; ++r) {
        #pragma unroll
        for (int off = 1; off < 16; off <<= 1)
            lp[r] += __shfl_xor(lp[r], off);
        const float inv = 1.0f / lp[r];
        const size_t row = (size_t)(qt * 64 + 16 * w + quad * 4 + r) * DM + (size_t)h * HD;
        #pragma unroll
        for (int db = 0; db < 4; ++db)
            AO[row + 16 * db + lm] = f2b(O[db][r] * inv);
    }
}

// ---------------------------------------------------------------- output proj
// Barrier-free: grid (16, 32), 4 waves 2x2, wave = 32x32 tile, direct frags.
__global__ __launch_bounds__(256) void oproj_mfma(
    const u16* __restrict__ AO, const u16* __restrict__ wot,
    const float* __restrict__ bo, float* __restrict__ out)
{
    const int t = threadIdx.x;
    const int w = t >> 6, lane = t & 63, lm = lane & 15, quad = lane >> 4;
    const int n0 = blockIdx.x * 64 + (w & 1) * 32;
    const int m0 = blockIdx.y * 64 + (w >> 1) * 32;

    const u16* arow[2] = { AO  + (size_t)(m0 + lm) * DM + quad * 8,
                           AO  + (size_t)(m0 + 16 + lm) * DM + quad * 8 };
    const u16* brow[2] = { wot + (size_t)(n0 + lm) * DM + quad * 8,
                           wot + (size_t)(n0 + 16 + lm) * DM + quad * 8 };

    f32x4 acc[2][2];
    #pragma unroll
    for (int i = 0; i < 2; ++i)
        #pragma unroll
        for (int j = 0; j < 2; ++j) acc[i][j] = (f32x4){0.f, 0.f, 0.f, 0.f};

    bf16x8 a0[2], b0[2], a1[2], b1[2];
    #pragma unroll
    for (int i = 0; i < 2; ++i) {
        a0[i] = *reinterpret_cast<const bf16x8*>(arow[i]);
        b0[i] = *reinterpret_cast<const bf16x8*>(brow[i]);
    }
    for (int k = 0; k < DM; k += 64) {
        #pragma unroll
        for (int i = 0; i < 2; ++i) {
            a1[i] = *reinterpret_cast<const bf16x8*>(arow[i] + k + 32);
            b1[i] = *reinterpret_cast<const bf16x8*>(brow[i] + k + 32);
        }
        #pragma unroll
        for (int mi = 0; mi < 2; ++mi)
            #pragma unroll
            for (int ni = 0; ni < 2; ++ni)
                acc[mi][ni] = __builtin_amdgcn_mfma_f32_16x16x32_bf16(a0[mi], b0[ni], acc[mi][ni], 0, 0, 0);
        if (k + 64 < DM) {
            #pragma unroll
            for (int i = 0; i < 2; ++i) {
                a0[i] = *reinterpret_cast<const bf16x8*>(arow[i] + k + 64);
                b0[i] = *reinterpret_cast<const bf16x8*>(brow[i] + k + 64);
            }
        }
        #pragma unroll
        for (int mi = 0; mi < 2; ++mi)
            #pragma unroll
            for (int ni = 0; ni < 2; ++ni)
                acc[mi][ni] = __builtin_amdgcn_mfma_f32_16x16x32_bf16(a1[mi], b1[ni], acc[mi][ni], 0, 0, 0);
    }

    #pragma unroll
    for (int mi = 0; mi < 2; ++mi)
        #pragma unroll
        for (int ni = 0; ni < 2; ++ni) {
            const int ncol = n0 + ni * 16 + lm;
            const float bvv = bo[ncol];
            #pragma unroll
            for (int r = 0; r < 4; ++r) {
                const int m = m0 + mi * 16 + quad * 4 + r;
                out[(size_t)m * DM + ncol] = acc[mi][ni][r] + bvv;
            }
        }
}

// ---------------------------------------------------------------- launcher
extern "C" void kernel_launch(void* const* d_in, const int* in_sizes, int n_in,
                              void* d_out, int out_size, void* d_ws, size_t ws_size,
                              hipStream_t stream)
{
    const float* q  = (const float*)d_in[0];
    const float* k  = (const float*)d_in[1];
    const float* v  = (const float*)d_in[2];
    // d_in[3] = mask (int32) — causal tril, handled analytically
    const float* Wq = (const float*)d_in[4];
    const float* bq = (const float*)d_in[5];
    const float* Wk = (const float*)d_in[6];
    const float* bk = (const float*)d_in[7];
    const float* Wv = (const float*)d_in[8];
    const float* bv = (const float*)d_in[9];
    const float* Wo = (const float*)d_in[10];
    const float* bo = (const float*)d_in[11];
    float* out = (float*)d_out;

    u16* Xq  = (u16*)d_ws;                          // [2048][1024] bf16
    u16* Xk  = Xq  + (size_t)SEQ * DM;
    u16* Xv  = Xk  + (size_t)SEQ * DM;
    u16* Wt  = Xv  + (size_t)SEQ * DM;              // [1536][1024]
    u16* wot = Wt  + (size_t)1536 * 1024;           // [1024][1024]
    u16* Qr  = wot + (size_t)1024 * 1024;           // [16][2048][64]
    u16* Kr  = Qr  + (size_t)16 * SEQ * HD;         // [4][2048][64]
    u16* Vrt = Kr  + (size_t)4 * SEQ * HD;          // [4][64][2048]
    u16* AO  = Vrt + (size_t)4 * SEQ * HD;          // [2048][1024]

    hipLaunchKernelGGL(prep_kernel, dim3(1408), dim3(256), 0, stream,
                       q, k, v, Wq, Wk, Wv, Wo, Xq, Xk, Xv, Wt, wot);
    hipLaunchKernelGGL(proj_mfma, dim3(24, 32), dim3(256), 0, stream,
                       Xq, Xk, Xv, Wt, bq, bk, bv, Qr, Kr, Vrt);
    hipLaunchKernelGGL(attn_mfma, dim3(16, 32), dim3(256), 0, stream,
                       Qr, Kr, Vrt, AO);
    hipLaunchKernelGGL(oproj_mfma, dim3(16, 32), dim3(256), 0, stream,
                       AO, wot, bo, out);
}

// Round 9
// 166.291 us; speedup vs baseline: 1.4958x; 1.4958x over previous
//
#include <hip/hip_runtime.h>
#include <hip/hip_bf16.h>
#include <math.h>

// GQA attention forward, MI355X. Round 9: r4 LDS-staged base +
//  - attn: 512-thr blocks, 2 q-tiles/block (qy, 31-qy), shared K/V staging,
//    dbuf + 1 barrier/tile, packed-P (b64 writes) with key-permuted V.
//  - proj/oproj: dbuf LDS + register prefetch, 1 barrier/k-iter.
// ws (u16): Xq 2M | Xk 2M | Xv 2M | Wt 1.5M | wot 1M | Qr 2M | Kr 512K | Vrt 512K | AO 2M

#define SEQ 2048
#define DM 1024
#define HD 64

using u16 = unsigned short;
typedef __attribute__((ext_vector_type(8))) short bf16x8;
typedef __attribute__((ext_vector_type(4))) float f32x4;

// 1/sqrt(64) * log2(e): softmax in exp2 domain.
#define QSCALE 0.18033688011112042f

__device__ __forceinline__ u16 f2b(float f) {              // RNE
    union { float f; unsigned int i; } v; v.f = f;
    unsigned int u = v.i;
    return (u16)((u + 0x7fffu + ((u >> 16) & 1u)) >> 16);
}
__device__ __forceinline__ u16 f2b_fast(float f) {         // biased round
    union { float f; unsigned int i; } v; v.f = f;
    return (u16)((v.i + 0x8000u) >> 16);
}

// ---------------------------------------------------------------- prep
// [0,640): weight 64x64 transposes fp32->bf16 row-major [n][k].
// [640,1408): q/k/v fp32 -> bf16 row-major.
__global__ __launch_bounds__(256) void prep_kernel(
    const float* __restrict__ qin, const float* __restrict__ kin, const float* __restrict__ vin,
    const float* __restrict__ Wq, const float* __restrict__ Wk,
    const float* __restrict__ Wv, const float* __restrict__ Wo,
    u16* __restrict__ Xq, u16* __restrict__ Xk, u16* __restrict__ Xv,
    u16* __restrict__ Wt, u16* __restrict__ wot)
{
    const int b = blockIdx.x;
    const int t = threadIdx.x;

    if (b < 640) {
        __shared__ short T[64][72];
        const float* W; u16* dst; int N, t0, rowoff;
        if (b < 256)      { W = Wq; dst = Wt;  N = 1024; t0 = b;       rowoff = 0; }
        else if (b < 320) { W = Wk; dst = Wt;  N = 256;  t0 = b - 256; rowoff = 1024; }
        else if (b < 384) { W = Wv; dst = Wt;  N = 256;  t0 = b - 320; rowoff = 1280; }
        else              { W = Wo; dst = wot; N = 1024; t0 = b - 384; rowoff = 0; }
        const int ntn = N >> 6;
        const int k0 = (t0 / ntn) * 64, n0 = (t0 % ntn) * 64;
        const int r = t >> 4, c4 = (t & 15) * 4;
        #pragma unroll
        for (int rr = 0; rr < 4; ++rr) {
            const int k = r + rr * 16;
            float4 w4 = *reinterpret_cast<const float4*>(W + (size_t)(k0 + k) * N + n0 + c4);
            T[c4 + 0][k] = (short)f2b(w4.x);
            T[c4 + 1][k] = (short)f2b(w4.y);
            T[c4 + 2][k] = (short)f2b(w4.z);
            T[c4 + 3][k] = (short)f2b(w4.w);
        }
        __syncthreads();
        const int n = t >> 2, ck = (t & 3) * 16;
        u16* dp = dst + (size_t)(rowoff + n0 + n) * DM + k0 + ck;
        *reinterpret_cast<bf16x8*>(dp)     = *reinterpret_cast<const bf16x8*>(&T[n][ck]);
        *reinterpret_cast<bf16x8*>(dp + 8) = *reinterpret_cast<const bf16x8*>(&T[n][ck + 8]);
    } else {
        const int idx = b - 640;
        const int which = idx >> 8;
        const int ib = idx & 255;
        const float* src = (which == 0) ? qin : (which == 1) ? kin : vin;
        u16* dst = (which == 0) ? Xq : (which == 1) ? Xk : Xv;
        const size_t base = (size_t)ib * 8192 + (size_t)t * 32;
        #pragma unroll
        for (int c = 0; c < 4; ++c) {
            float4 x0 = *reinterpret_cast<const float4*>(src + base + c * 8);
            float4 x1 = *reinterpret_cast<const float4*>(src + base + c * 8 + 4);
            bf16x8 o;
            o[0] = (short)f2b(x0.x); o[1] = (short)f2b(x0.y);
            o[2] = (short)f2b(x0.z); o[3] = (short)f2b(x0.w);
            o[4] = (short)f2b(x1.x); o[5] = (short)f2b(x1.y);
            o[6] = (short)f2b(x1.z); o[7] = (short)f2b(x1.w);
            *reinterpret_cast<bf16x8*>(dst + base + c * 8) = o;
        }
    }
}

// ---------------------------------------------------------------- projections
// Unified QKV: grid (24, 32), 64x64 tile, BK=64, dbuf + reg prefetch,
// 1 barrier/iter. Cols [0,1024)=Q (RoPE*QSCALE), [1024,1280)=K (RoPE),
// [1280,1536)=V (transposed + key-permuted store).
__global__ __launch_bounds__(256) void proj_mfma(
    const u16* __restrict__ Xq, const u16* __restrict__ Xk, const u16* __restrict__ Xv,
    const u16* __restrict__ Wt,
    const float* __restrict__ bq, const float* __restrict__ bk, const float* __restrict__ bv,
    u16* __restrict__ Qr, u16* __restrict__ Kr, u16* __restrict__ Vrt)
{
    const int n0 = blockIdx.x * 64, m0 = blockIdx.y * 64;
    const int zone = (n0 < 1024) ? 0 : (n0 < 1280) ? 1 : 2;
    const u16* __restrict__ Az = (zone == 0) ? Xq : (zone == 1) ? Xk : Xv;

    __shared__ short As[2][64][72];
    __shared__ short Bs[2][64][72];

    const int t = threadIdx.x;
    const int w = t >> 6, lane = t & 63, lm = lane & 15, quad = lane >> 4;
    const int sr = t >> 2, sc = (t & 3) * 16;

    f32x4 acc[4] = { {0,0,0,0}, {0,0,0,0}, {0,0,0,0}, {0,0,0,0} };

    const u16* ap_ = Az + (size_t)(m0 + sr) * DM + sc;
    const u16* bp_ = Wt + (size_t)(n0 + sr) * DM + sc;
    bf16x8 aR0 = *reinterpret_cast<const bf16x8*>(ap_);
    bf16x8 aR1 = *reinterpret_cast<const bf16x8*>(ap_ + 8);
    bf16x8 bR0 = *reinterpret_cast<const bf16x8*>(bp_);
    bf16x8 bR1 = *reinterpret_cast<const bf16x8*>(bp_ + 8);

    for (int k0 = 0; k0 < DM; k0 += 64) {
        const int buf = (k0 >> 6) & 1;
        *reinterpret_cast<bf16x8*>(&As[buf][sr][sc])     = aR0;
        *reinterpret_cast<bf16x8*>(&As[buf][sr][sc + 8]) = aR1;
        *reinterpret_cast<bf16x8*>(&Bs[buf][sr][sc])     = bR0;
        *reinterpret_cast<bf16x8*>(&Bs[buf][sr][sc + 8]) = bR1;
        if (k0 + 64 < DM) {
            aR0 = *reinterpret_cast<const bf16x8*>(ap_ + k0 + 64);
            aR1 = *reinterpret_cast<const bf16x8*>(ap_ + k0 + 72);
            bR0 = *reinterpret_cast<const bf16x8*>(bp_ + k0 + 64);
            bR1 = *reinterpret_cast<const bf16x8*>(bp_ + k0 + 72);
        }
        __syncthreads();
        bf16x8 af0 = *reinterpret_cast<const bf16x8*>(&As[buf][16 * w + lm][quad * 8]);
        bf16x8 af1 = *reinterpret_cast<const bf16x8*>(&As[buf][16 * w + lm][32 + quad * 8]);
        #pragma unroll
        for (int nb = 0; nb < 4; ++nb) {
            bf16x8 b0 = *reinterpret_cast<const bf16x8*>(&Bs[buf][16 * nb + lm][quad * 8]);
            bf16x8 b1 = *reinterpret_cast<const bf16x8*>(&Bs[buf][16 * nb + lm][32 + quad * 8]);
            acc[nb] = __builtin_amdgcn_mfma_f32_16x16x32_bf16(af0, b0, acc[nb], 0, 0, 0);
            acc[nb] = __builtin_amdgcn_mfma_f32_16x16x32_bf16(af1, b1, acc[nb], 0, 0, 0);
        }
        __syncthreads();   // protects As/Bs[buf] reads vs next iter's writes? no:
                           // next iter writes buf^1; this barrier separates compute
                           // from the *following* write to this buf two iters on.
    }

    const float* __restrict__ bias = (zone == 0) ? bq : (zone == 1) ? bk : bv;
    const int nbase = (zone == 0) ? n0 : (zone == 1) ? (n0 - 1024) : (n0 - 1280);
    const int head = nbase >> 6;
    #pragma unroll
    for (int nb = 0; nb < 4; ++nb) {
        const int d = 16 * nb + lm;
        const float bvv = bias[nbase + d];
        float vals[4];
        #pragma unroll
        for (int r = 0; r < 4; ++r) vals[r] = acc[nb][r] + bvv;
        if (zone != 2) {
            const int pi = d >> 1;
            const float theta = exp2f(-0.8304820237f * (float)pi);  // 10000^(-pi/16)
            const bool odd = (lm & 1);
            const float sca = (zone == 0) ? QSCALE : 1.0f;
            u16* op = (zone == 0 ? Qr : Kr) + (size_t)head * SEQ * HD;
            #pragma unroll
            for (int r = 0; r < 4; ++r) {
                const int m = m0 + 16 * w + quad * 4 + r;
                float sn, cs;
                sincosf((float)m * theta, &sn, &cs);
                float x  = vals[r];
                float xp = __shfl_xor(x, 1);
                float o  = (odd ? (xp * sn + x * cs) : (x * cs - xp * sn)) * sca;
                op[(size_t)m * HD + d] = f2b(o);
            }
        } else {
            // V transposed [kvh][d][pos], key-PERMUTED within each 64-tile:
            // within = m&63 -> pos = tile*64 + 4*(within&15) + (within>>4)
            u16* vp = Vrt + ((size_t)head * HD + d) * SEQ;
            #pragma unroll
            for (int r = 0; r < 4; ++r) {
                const int m = m0 + 16 * w + quad * 4 + r;
                const int within = m & 63;
                const int pos = (m & ~63) + 4 * (within & 15) + (within >> 4);
                vp[pos] = f2b(vals[r]);
            }
        }
    }
}

// ---------------------------------------------------------------- attention
// grid (16 heads, 16 qy), 512 threads (8 waves, 2 teams of 4).
// Team 0: q-tile qy; team 1: q-tile 31-qy (constant 33 tile-computations).
// K/V staged once per kt for both teams (dbuf, 1 barrier/tile, reg prefetch).
// P: packed col-permuted LDS (c = 4*lm + nb) -> 4x ds_write_b64; V global
// layout is key-permuted to match. Fixed-base exp2 softmax.
__global__ __launch_bounds__(512) void attn_mfma(
    const u16* __restrict__ Qr, const u16* __restrict__ Kr, const u16* __restrict__ Vrt,
    u16* __restrict__ AO)
{
    const int h  = blockIdx.x;
    const int qy = blockIdx.y;
    const int kvh = h & 3;

    __shared__ u16 Ks[2][64][72];     // [key][d]
    __shared__ u16 Vt[2][64][72];     // [d][c]  (c = permuted key)
    __shared__ u16 Ps[8][16][76];     // per-wave strip; also Q staging

    const int t = threadIdx.x;
    const int w = t >> 6, lane = t & 63, lm = lane & 15, quad = lane >> 4;
    const int team = w >> 2, wt = w & 3;
    const int qt  = team ? (31 - qy) : qy;
    const int qtb = 31 - qy;                      // = max(qt of both teams)

    {   // stage this wave's 16 Q rows into its Ps strip (wave-private)
        const int row = lane >> 2, c = (lane & 3) * 16;
        const u16* qp = Qr + ((size_t)h * SEQ + qt * 64 + wt * 16 + row) * HD + c;
        *reinterpret_cast<bf16x8*>(&Ps[w][row][c])     = *reinterpret_cast<const bf16x8*>(qp);
        *reinterpret_cast<bf16x8*>(&Ps[w][row][c + 8]) = *reinterpret_cast<const bf16x8*>(qp + 8);
    }
    const bf16x8 aq0 = *reinterpret_cast<const bf16x8*>(&Ps[w][lm][quad * 8]);
    const bf16x8 aq1 = *reinterpret_cast<const bf16x8*>(&Ps[w][lm][32 + quad * 8]);

    f32x4 O[4] = { {0,0,0,0}, {0,0,0,0}, {0,0,0,0}, {0,0,0,0} };   // C[q=quad*4+r][d=16db+lm]
    float lp[4] = { 0.f, 0.f, 0.f, 0.f };

    // staging: 512 threads, 1 b128 each for K and V
    const int srow = t >> 3, sc2 = (t & 7) * 8;
    const u16* kb_ = Kr  + ((size_t)kvh * SEQ + srow) * HD + sc2;   // + kt*64*HD
    const u16* vb_ = Vrt + ((size_t)kvh * HD + srow) * SEQ + sc2;   // + kt*64
    bf16x8 kR = *reinterpret_cast<const bf16x8*>(kb_);
    bf16x8 vR = *reinterpret_cast<const bf16x8*>(vb_);

    for (int kt = 0; kt <= qtb; ++kt) {
        const int buf = kt & 1;
        *reinterpret_cast<bf16x8*>(&Ks[buf][srow][sc2]) = kR;
        *reinterpret_cast<bf16x8*>(&Vt[buf][srow][sc2]) = vR;
        if (kt < qtb) {
            kR = *reinterpret_cast<const bf16x8*>(kb_ + (size_t)(kt + 1) * 64 * HD);
            vR = *reinterpret_cast<const bf16x8*>(vb_ + (size_t)(kt + 1) * 64);
        }
        __syncthreads();

        if (kt <= qt) {
            f32x4 s[4];
            #pragma unroll
            for (int nb = 0; nb < 4; ++nb) {
                bf16x8 b0 = *reinterpret_cast<const bf16x8*>(&Ks[buf][16 * nb + lm][quad * 8]);
                bf16x8 b1 = *reinterpret_cast<const bf16x8*>(&Ks[buf][16 * nb + lm][32 + quad * 8]);
                f32x4 zz = { 0.f, 0.f, 0.f, 0.f };
                zz = __builtin_amdgcn_mfma_f32_16x16x32_bf16(aq0, b0, zz, 0, 0, 0);
                s[nb] = __builtin_amdgcn_mfma_f32_16x16x32_bf16(aq1, b1, zz, 0, 0, 0);
            }

            if (kt == qt) {   // causal mask (col=16nb+lm, row=16wt+quad*4+r)
                #pragma unroll
                for (int nb = 0; nb < 4; ++nb)
                    #pragma unroll
                    for (int r = 0; r < 4; ++r)
                        if (16 * nb + lm > 16 * wt + quad * 4 + r) s[nb][r] = -INFINITY;
            }

            // exp2 + packed P write: row quad*4+r, cols c=4*lm..4*lm+3 (nb)
            #pragma unroll
            for (int r = 0; r < 4; ++r) {
                u16 pk[4];
                #pragma unroll
                for (int nb = 0; nb < 4; ++nb) {
                    float e = __builtin_amdgcn_exp2f(fminf(s[nb][r], 126.f));
                    lp[r] += e;
                    pk[nb] = f2b_fast(e);
                }
                *reinterpret_cast<uint2*>(&Ps[w][quad * 4 + r][4 * lm]) =
                    *reinterpret_cast<uint2*>(pk);
            }

            const bf16x8 ap0 = *reinterpret_cast<const bf16x8*>(&Ps[w][lm][quad * 8]);
            const bf16x8 ap1 = *reinterpret_cast<const bf16x8*>(&Ps[w][lm][32 + quad * 8]);
            #pragma unroll
            for (int db = 0; db < 4; ++db) {
                bf16x8 v0 = *reinterpret_cast<const bf16x8*>(&Vt[buf][16 * db + lm][quad * 8]);
                bf16x8 v1 = *reinterpret_cast<const bf16x8*>(&Vt[buf][16 * db + lm][32 + quad * 8]);
                O[db] = __builtin_amdgcn_mfma_f32_16x16x32_bf16(ap0, v0, O[db], 0, 0, 0);
                O[db] = __builtin_amdgcn_mfma_f32_16x16x32_bf16(ap1, v1, O[db], 0, 0, 0);
            }
        }
    }

    #pragma unroll
    for (int r = 0; r < 4; ++r) {
        #pragma unroll
        for (int off = 1; off < 16; off <<= 1)
            lp[r] += __shfl_xor(lp[r], off);
        const float inv = 1.0f / lp[r];
        const size_t row = (size_t)(qt * 64 + 16 * wt + quad * 4 + r) * DM + (size_t)h * HD;
        #pragma unroll
        for (int db = 0; db < 4; ++db)
            AO[row + 16 * db + lm] = f2b(O[db][r] * inv);
    }
}

// ---------------------------------------------------------------- output proj
// grid (16, 32): AO bf16 @ Wo^T bf16 + bo -> fp32 out. BK=64, dbuf + prefetch.
__global__ __launch_bounds__(256) void oproj_mfma(
    const u16* __restrict__ AO, const u16* __restrict__ wot,
    const float* __restrict__ bo, float* __restrict__ out)
{
    __shared__ short As[2][64][72];
    __shared__ short Bs[2][64][72];
    const int t = threadIdx.x;
    const int w = t >> 6, lane = t & 63, lm = lane & 15, quad = lane >> 4;
    const int m0 = blockIdx.y * 64, n0 = blockIdx.x * 64;
    const int sr = t >> 2, sc = (t & 3) * 16;

    f32x4 acc[4] = { {0,0,0,0}, {0,0,0,0}, {0,0,0,0}, {0,0,0,0} };

    const u16* ap_ = AO  + (size_t)(m0 + sr) * DM + sc;
    const u16* bp_ = wot + (size_t)(n0 + sr) * DM + sc;
    bf16x8 aR0 = *reinterpret_cast<const bf16x8*>(ap_);
    bf16x8 aR1 = *reinterpret_cast<const bf16x8*>(ap_ + 8);
    bf16x8 bR0 = *reinterpret_cast<const bf16x8*>(bp_);
    bf16x8 bR1 = *reinterpret_cast<const bf16x8*>(bp_ + 8);

    for (int k0 = 0; k0 < DM; k0 += 64) {
        const int buf = (k0 >> 6) & 1;
        *reinterpret_cast<bf16x8*>(&As[buf][sr][sc])     = aR0;
        *reinterpret_cast<bf16x8*>(&As[buf][sr][sc + 8]) = aR1;
        *reinterpret_cast<bf16x8*>(&Bs[buf][sr][sc])     = bR0;
        *reinterpret_cast<bf16x8*>(&Bs[buf][sr][sc + 8]) = bR1;
        if (k0 + 64 < DM) {
            aR0 = *reinterpret_cast<const bf16x8*>(ap_ + k0 + 64);
            aR1 = *reinterpret_cast<const bf16x8*>(ap_ + k0 + 72);
            bR0 = *reinterpret_cast<const bf16x8*>(bp_ + k0 + 64);
            bR1 = *reinterpret_cast<const bf16x8*>(bp_ + k0 + 72);
        }
        __syncthreads();
        bf16x8 af0 = *reinterpret_cast<const bf16x8*>(&As[buf][16 * w + lm][quad * 8]);
        bf16x8 af1 = *reinterpret_cast<const bf16x8*>(&As[buf][16 * w + lm][32 + quad * 8]);
        #pragma unroll
        for (int nb = 0; nb < 4; ++nb) {
            bf16x8 b0 = *reinterpret_cast<const bf16x8*>(&Bs[buf][16 * nb + lm][quad * 8]);
            bf16x8 b1 = *reinterpret_cast<const bf16x8*>(&Bs[buf][16 * nb + lm][32 + quad * 8]);
            acc[nb] = __builtin_amdgcn_mfma_f32_16x16x32_bf16(af0, b0, acc[nb], 0, 0, 0);
            acc[nb] = __builtin_amdgcn_mfma_f32_16x16x32_bf16(af1, b1, acc[nb], 0, 0, 0);
        }
        __syncthreads();
    }

    #pragma unroll
    for (int nb = 0; nb < 4; ++nb) {
        const int dl = 16 * nb + lm;
        const float bv = bo[n0 + dl];
        #pragma unroll
        for (int r = 0; r < 4; ++r) {
            const int m = m0 + 16 * w + quad * 4 + r;
            out[(size_t)m * DM + n0 + dl] = acc[nb][r] + bv;
        }
    }
}

// ---------------------------------------------------------------- launcher
extern "C" void kernel_launch(void* const* d_in, const int* in_sizes, int n_in,
                              void* d_out, int out_size, void* d_ws, size_t ws_size,
                              hipStream_t stream)
{
    const float* q  = (const float*)d_in[0];
    const float* k  = (const float*)d_in[1];
    const float* v  = (const float*)d_in[2];
    // d_in[3] = mask (int32) — causal tril, handled analytically
    const float* Wq = (const float*)d_in[4];
    const float* bq = (const float*)d_in[5];
    const float* Wk = (const float*)d_in[6];
    const float* bk = (const float*)d_in[7];
    const float* Wv = (const float*)d_in[8];
    const float* bv = (const float*)d_in[9];
    const float* Wo = (const float*)d_in[10];
    const float* bo = (const float*)d_in[11];
    float* out = (float*)d_out;

    u16* Xq  = (u16*)d_ws;                          // [2048][1024] bf16
    u16* Xk  = Xq  + (size_t)SEQ * DM;
    u16* Xv  = Xk  + (size_t)SEQ * DM;
    u16* Wt  = Xv  + (size_t)SEQ * DM;              // [1536][1024]
    u16* wot = Wt  + (size_t)1536 * 1024;           // [1024][1024]
    u16* Qr  = wot + (size_t)1024 * 1024;           // [16][2048][64]
    u16* Kr  = Qr  + (size_t)16 * SEQ * HD;         // [4][2048][64]
    u16* Vrt = Kr  + (size_t)4 * SEQ * HD;          // [4][64][2048] key-permuted
    u16* AO  = Vrt + (size_t)4 * SEQ * HD;          // [2048][1024]

    hipLaunchKernelGGL(prep_kernel, dim3(1408), dim3(256), 0, stream,
                       q, k, v, Wq, Wk, Wv, Wo, Xq, Xk, Xv, Wt, wot);
    hipLaunchKernelGGL(proj_mfma, dim3(24, 32), dim3(256), 0, stream,
                       Xq, Xk, Xv, Wt, bq, bk, bv, Qr, Kr, Vrt);
    hipLaunchKernelGGL(attn_mfma, dim3(16, 16), dim3(512), 0, stream,
                       Qr, Kr, Vrt, AO);
    hipLaunchKernelGGL(oproj_mfma, dim3(16, 32), dim3(256), 0, stream,
                       AO, wot, bo, out);
}